// Round 18
// baseline (1470.934 us; speedup 1.0000x reference)
//
#include <hip/hip_runtime.h>
#include <hip/hip_bf16.h>

#define IN_C 8
#define HID 64
#define N_NODES 20000
#define WINDOW 8
#define N_BIG 160000
#define NE 1600000
#define E_DEC 500000
#define DHV 143
#define EPSV 1e-5f
#define CAP 32
#define OVF_CAP 4096
#define NER 168   // padded LDS row stride (shorts) for the pq embedding tile
#define QS 16384.0f
#define IQS (1.0f / 16384.0f)
#define NPART 8
#define PART_SZ (N_BIG / NPART)     // 20000
#define NEB (NE / 256)              // 6250 edge chunks
#define NFILL 4096                  // persistent fill blocks
// s_getreg imm: hwreg(HW_REG_XCC_ID=20, offset=0, width=4) = 20 | (3<<11)
#define XCC_HWREG 6164

typedef __hip_bfloat16 bf;
typedef __attribute__((ext_vector_type(8))) short short8;
typedef __attribute__((ext_vector_type(4))) float float4_;

__device__ __forceinline__ float b2f(bf v) { return __bfloat162float(v); }
__device__ __forceinline__ bf f2b(float v) { return __float2bfloat16(v); }
__device__ __forceinline__ float bflo(unsigned int u) { return __uint_as_float(u << 16); }
__device__ __forceinline__ float bfhi(unsigned int u) { return __uint_as_float(u & 0xffff0000u); }
__device__ __forceinline__ unsigned int packbf2(float lo, float hi) {
    unsigned int ul = __bfloat16_as_ushort(f2b(lo));
    unsigned int uh = __bfloat16_as_ushort(f2b(hi));
    return ul | (uh << 16);
}
__device__ __forceinline__ float sigf(float x) {
    return __builtin_amdgcn_rcpf(1.f + __expf(-x));
}
__device__ __forceinline__ float tanhfast(float x) {
    x = fminf(fmaxf(x, -15.f), 15.f);
    float e = __expf(2.f * x);
    return (e - 1.f) * __builtin_amdgcn_rcpf(e + 1.f);
}

// ------- XCD-aware work-stealing bucket fill + prep grid-split --------------
// Fill blocks read their REAL XCD id (s_getreg HW_REG_XCC_ID) and drain the
// chunk-cursor of their own destination partition first -> a partition's
// 2.56MB bucket slice is written by ONE XCD's L2 and its ~10 stores/line
// merge before writeback. Fallback sweep over other partitions guarantees
// every (partition, chunk) is processed exactly once regardless of mapping.
__global__ __launch_bounds__(256) void k_prepfill(
    const int* ei, const float* ea, int* cnt, unsigned int* bucket, int* ovfn, int* cursor,
    float4* ovf,
    const float* Wih2, const float* Whh2, const float* bih1, const float* bhh1,
    const float* bih2, const float* bhh2, const float* dWa,
    bf* B2f, float* bc1, float* bc2, bf* Bpqf)
{
    int tid = threadIdx.x;
    if (blockIdx.x < NFILL) {
        __shared__ int chunk_s;
        int xcd = (int)(__builtin_amdgcn_s_getreg(XCC_HWREG)) & (NPART - 1);
        for (int pp = 0; pp < NPART; pp++) {
            int p = (xcd + pp) & (NPART - 1);
            int lo = p * PART_SZ, hi = lo + PART_SZ;
            for (;;) {
                if (tid == 0) chunk_s = atomicAdd(&cursor[p], 1);
                __syncthreads();
                int chunk = chunk_s;
                __syncthreads();
                if (chunk >= NEB) break;
                int e = chunk * 256 + tid;
                int c = ei[NE + e];
                if (c >= lo && c < hi) {
                    int r = ei[e];
                    float a = ea[e];
                    unsigned int q = (unsigned int)(a * QS + 0.5f);
                    if (q > 16383u) q = 16383u;
                    int ppos = atomicAdd(&cnt[c], 1);
                    if (ppos < CAP) bucket[(size_t)c * CAP + ppos] = ((unsigned int)r << 14) | q;
                    else {
                        int qq = atomicAdd(ovfn, 1);
                        if (qq < OVF_CAP) ovf[qq] = make_float4(__int_as_float(c), __int_as_float(r), a, 0.f);
                    }
                }
            }
        }
        return;
    }
    int i0 = (blockIdx.x - NFILL) * 256 + tid;
    int stride = 512 * 256;
    for (int i = i0; i < 16 * 4 * 64 * 8; i += stride) {   // B2 fragments (K=128)
        int j = i & 7, lane = (i >> 3) & 63, r = i >> 9;
        int c = r & 3, ct = r >> 2;
        int q = lane >> 4, l15 = lane & 15;
        int n = ct * 16 + l15, k = c * 32 + q * 8 + j;
        B2f[i] = f2b((k < 64) ? Wih2[n * 64 + k] : Whh2[n * 64 + (k - 64)]);
    }
    for (int i = i0; i < 256; i += stride) {
        bc1[i] = bih1[i] + bhh1[i];
        bc2[i] = bih2[i] + bhh2[i];
    }
    for (int i = i0; i < 18 * 5 * 64 * 8; i += stride) {   // decoder fragments
        int j = i & 7, lane = (i >> 3) & 63, r = i >> 9;
        int c = r % 5, ct = r / 5;
        int q = lane >> 4, l15 = lane & 15;
        int n = ct * 16 + l15, k = c * 32 + q * 8 + j;
        float v = 0.f;
        if (k < DHV) {
            if (n < DHV) v = dWa[k * DHV + n];
            else if (n >= 144 && n < 144 + DHV) v = dWa[(DHV + k) * DHV + (n - 144)];
        }
        Bpqf[i] = f2b(v);
    }
}

// -------- fused: deg from buckets -> dis; write dis*(x@W1) once ------------
__global__ __launch_bounds__(256) void k_xw1dis(const float* x, const float* W1,
        const int* cnt, const unsigned int* bucket, const int* ovfn, const float4* ovf,
        float* dis, bf* hbufb) {
    __shared__ float Ws[8][64];
    __shared__ float xs[8][8];
    int tid = threadIdx.x;
    Ws[tid >> 6][tid & 63] = W1[tid];
    Ws[4 + (tid >> 6)][tid & 63] = W1[256 + tid];
    int nb0 = blockIdx.x * 8;
    if (tid < 64) xs[tid >> 3][tid & 7] = x[nb0 * IN_C + tid];
    __syncthreads();
    int wv = tid >> 6, half = (tid >> 5) & 1, l = tid & 31;
    int nl = wv * 2 + half;
    int c = nb0 + nl;
    int n = cnt[c];
    int nbk = (n < CAP) ? n : CAP;
    float s = 0.f;
    for (int i = l; i < nbk; i += 32) s += (float)(bucket[(size_t)c * CAP + i] & 0x3FFFu);
    s *= IQS;
    if (n > CAP) {
        int m = *ovfn; if (m > OVF_CAP) m = OVF_CAP;
        for (int i = l; i < m; i += 32) {
            float4 v = ovf[i];
            if (__float_as_int(v.x) == c) s += v.z;
        }
    }
#pragma unroll
    for (int off = 16; off > 0; off >>= 1) s += __shfl_xor(s, off);
    float dv = rsqrtf(fmaxf(1.f + s, EPSV));
    if (l == 0) dis[c] = dv;
    float a0 = 0.f, a1 = 0.f;
#pragma unroll
    for (int k = 0; k < IN_C; k++) {
        float xv = xs[nl][k];
        a0 += xv * Ws[k][2 * l];
        a1 += xv * Ws[k][2 * l + 1];
    }
    *(unsigned int*)(hbufb + (size_t)c * 64 + 2 * l) = packbf2(dv * a0, dv * a1);
}

// ---------------- GCN aggregation (bucket gather) + fused BN partial stats --
__global__ __launch_bounds__(256) void k_gcn_gather(const bf* h, const float* dis, const int* cnt,
                             const unsigned int* bucket, const int* ovfn, const float4* ovf,
                             const float* bias, bf* outb, float* part) {
    __shared__ float4 red[256];
    int tid = threadIdx.x;
    int wv = (blockIdx.x * 256 + tid) >> 6;
    int half = (tid >> 5) & 1, l = tid & 31;
    int c = wv * 2 + half;                 // grid exact: c < N_BIG always
    unsigned int hv = *(const unsigned int*)(h + (size_t)c * 64 + 2 * l);
    float ax = bflo(hv), ay = bfhi(hv);
    size_t o = (size_t)c * CAP;
    int nfull = cnt[c];
    int n = (nfull < CAP) ? nfull : CAP;
    int e = 0;
    for (; e + 8 <= n; e += 8) {
        unsigned int p[8];
#pragma unroll
        for (int j = 0; j < 8; j++) p[j] = bucket[o + e + j];
        unsigned int v[8];
#pragma unroll
        for (int j = 0; j < 8; j++)
            v[j] = *(const unsigned int*)(h + (size_t)(p[j] >> 14) * 64 + 2 * l);
#pragma unroll
        for (int j = 0; j < 8; j++) {
            float a = (float)(p[j] & 0x3FFFu) * IQS;
            ax += a * bflo(v[j]); ay += a * bfhi(v[j]);
        }
    }
    for (; e + 4 <= n; e += 4) {
        unsigned int p[4];
#pragma unroll
        for (int j = 0; j < 4; j++) p[j] = bucket[o + e + j];
        unsigned int v[4];
#pragma unroll
        for (int j = 0; j < 4; j++)
            v[j] = *(const unsigned int*)(h + (size_t)(p[j] >> 14) * 64 + 2 * l);
#pragma unroll
        for (int j = 0; j < 4; j++) {
            float a = (float)(p[j] & 0x3FFFu) * IQS;
            ax += a * bflo(v[j]); ay += a * bfhi(v[j]);
        }
    }
    for (; e < n; e++) {
        unsigned int p = bucket[o + e];
        unsigned int v = *(const unsigned int*)(h + (size_t)(p >> 14) * 64 + 2 * l);
        float a = (float)(p & 0x3FFFu) * IQS;
        ax += a * bflo(v);
        ay += a * bfhi(v);
    }
    if (nfull > CAP) {      // practically never
        int m = *ovfn; if (m > OVF_CAP) m = OVF_CAP;
        for (int i = 0; i < m; i++) {
            float4 v = ovf[i];
            if (__float_as_int(v.x) == c) {
                unsigned int hw = *(const unsigned int*)(h + (size_t)__float_as_int(v.y) * 64 + 2 * l);
                ax += v.z * bflo(hw);
                ay += v.z * bfhi(hw);
            }
        }
    }
    float dv = dis[c];
    float2 bv = *(const float2*)(bias + 2 * l);
    float vx = fmaxf(dv * ax + bv.x, 0.f);
    float vy = fmaxf(dv * ay + bv.y, 0.f);
    *(unsigned int*)(outb + (size_t)c * 64 + 2 * l) = packbf2(vx, vy);
    // ---- BN partial stats (fp32, pre-round) ----
    red[tid] = make_float4(vx, vy, vx * vx, vy * vy);
    __syncthreads();
    if (tid < 32) {
        float4 s = make_float4(0.f, 0.f, 0.f, 0.f);
#pragma unroll
        for (int i = 0; i < 8; i++) {
            float4 v = red[((i >> 1) << 6) + ((i & 1) << 5) + tid];
            s.x += v.x; s.y += v.y; s.z += v.z; s.w += v.w;
        }
        float* pb = part + (size_t)blockIdx.x * 128;
        pb[2 * tid] = s.x; pb[2 * tid + 1] = s.y;
        pb[64 + 2 * tid] = s.z; pb[64 + 2 * tid + 1] = s.w;
    }
}

// ---------------- reduce per-block BN partials ------------------------------
__global__ __launch_bounds__(256) void k_bnred(const float* part, int nblk, float* stats_out) {
    __shared__ float s[256];
    float acc = 0.f;
    for (int b = threadIdx.x; b < nblk; b += 256) acc += part[(size_t)b * 128 + blockIdx.x];
    s[threadIdx.x] = acc;
    __syncthreads();
    for (int off = 128; off; off >>= 1) {
        if (threadIdx.x < off) s[threadIdx.x] += s[threadIdx.x + off];
        __syncthreads();
    }
    if (threadIdx.x == 0) stats_out[blockIdx.x] = s[0];
}

// ------------------------------- fold BN1 affine into W2^T + bias ----------
__global__ __launch_bounds__(256) void k_fold1(const float* W2, const float* g1, const float* be1,
                                               const float* stats, bf* W2t, float* w2b, float* AC) {
    __shared__ float A[64], C[64];
    int tid = threadIdx.x;
    if (tid < 64) {
        float m = stats[tid] * (1.f / (float)N_BIG);
        float var = stats[64 + tid] * (1.f / (float)N_BIG) - m * m;
        float a = g1[tid] * rsqrtf(var + EPSV);
        float c = be1[tid] - m * a;
        A[tid] = a; C[tid] = c;
        AC[tid] = a; AC[64 + tid] = c;
    }
    __syncthreads();
    for (int i = tid; i < 4096; i += 256) {
        int n = i >> 6, k = i & 63;
        W2t[i] = f2b(W2[k * 64 + n] * A[k]);
    }
    if (tid < 64) {
        float s = 0.f;
        for (int k = 0; k < 64; k++) s += C[k] * W2[k * 64 + tid];
        w2b[tid] = s;
    }
}

// -------- fold BN1/BN2 affine into LSTM1 weights (B1f fragments) + bias ----
__global__ void k_fold2(const float* Wih1, const float* Whh1,
                        const float* g2, const float* be2, const float* stats,
                        const float* AC, const float* bih1, const float* bhh1,
                        bf* B1f, float* bc1f) {
    int i0 = blockIdx.x * blockDim.x + threadIdx.x;
    int stride = gridDim.x * blockDim.x;
    for (int i = i0; i < 16 * 6 * 64 * 8; i += stride) {
        int j = i & 7, lane = (i >> 3) & 63, r = i >> 9;
        int c = r % 6, ct = r / 6;
        int q = lane >> 4, l15 = lane & 15;
        int n = ct * 16 + l15, k = c * 32 + q * 8 + j;
        float w = (k < 128) ? Wih1[n * 128 + k] : Whh1[n * 64 + (k - 128)];
        float scale = 1.f;
        if (k < 64) scale = AC[k];
        else if (k < 128) {
            int ch = k - 64;
            float m = stats[128 + ch] * (1.f / (float)N_BIG);
            float var = stats[192 + ch] * (1.f / (float)N_BIG) - m * m;
            scale = g2[ch] * rsqrtf(var + EPSV);
        }
        B1f[i] = f2b(w * scale);
    }
    for (int n = i0; n < 256; n += stride) {
        float s = bih1[n] + bhh1[n];
        for (int k = 0; k < 64; k++) s += AC[64 + k] * Wih1[n * 128 + k];
        for (int ch = 0; ch < 64; ch++) {
            float m = stats[128 + ch] * (1.f / (float)N_BIG);
            float var = stats[192 + ch] * (1.f / (float)N_BIG) - m * m;
            float a = g2[ch] * rsqrtf(var + EPSV);
            float c2v = be2[ch] - m * a;
            s += c2v * Wih1[n * 128 + 64 + ch];
        }
        bc1f[n] = s;
    }
}

// ------------- h1_raw @ (A1-scaled W2) + w2b, epilogue x dis (bf16 MFMA) ----
__global__ __launch_bounds__(256) void k_h1w2(const bf* h1b, const bf* W2t, const float* w2b,
                                              const float* dis, bf* outb) {
    int tid = threadIdx.x, w = tid >> 6, lane = tid & 63;
    int q = lane >> 4, l15 = lane & 15;
    size_t r0 = (size_t)blockIdx.x * 64 + w * 16;
    float4_ acc[4];
#pragma unroll
    for (int ct = 0; ct < 4; ct++) acc[ct] = (float4_){0.f, 0.f, 0.f, 0.f};
#pragma unroll
    for (int c = 0; c < 2; c++) {
        int koff = c * 32 + q * 8;
        short8 a = *(const short8*)(h1b + (r0 + l15) * 64 + koff);
#pragma unroll
        for (int ct = 0; ct < 4; ct++) {
            short8 b = *(const short8*)(W2t + (size_t)(ct * 16 + l15) * 64 + koff);
            acc[ct] = __builtin_amdgcn_mfma_f32_16x16x32_bf16(a, b, acc[ct], 0, 0, 0);
        }
    }
    size_t node0 = r0 + q * 4;
#pragma unroll
    for (int reg = 0; reg < 4; reg++) {
        float dv = dis[node0 + reg];
#pragma unroll
        for (int ct = 0; ct < 4; ct++)
            outb[(node0 + reg) * 64 + ct * 16 + l15] = f2b(dv * (acc[ct][reg] + w2b[ct * 16 + l15]));
    }
}

// ----------------------------------------- fully fused double LSTM (MFMA) ---
__global__ __launch_bounds__(256, 1) void k_lstm_fused(
    const bf* h1b, const bf* h2b, const bf* B1f, const bf* B2f,
    const float* bc1, const float* bc2, bf* H1out, bf* H2out)
{
    __shared__ bf h1s[2][32][72];
    __shared__ bf h2s[2][32][72];
    int tid = threadIdx.x, w = tid >> 6, lane = tid & 63;
    int q = lane >> 4, l15 = lane & 15;
    int gnode0 = blockIdx.x * 32;
    short8 B1r[6][4];
    short8 B2r[4][4];
#pragma unroll
    for (int c = 0; c < 6; c++)
#pragma unroll
        for (int g = 0; g < 4; g++)
            B1r[c][g] = *(const short8*)(B1f + (size_t)(((w + 4 * g) * 6 + c) * 64 + lane) * 8);
#pragma unroll
    for (int c = 0; c < 4; c++)
#pragma unroll
        for (int g = 0; g < 4; g++)
            B2r[c][g] = *(const short8*)(B2f + (size_t)(((w + 4 * g) * 4 + c) * 64 + lane) * 8);
    float c1[2][4] = {}, c2[2][4] = {};
    float bv1[4], bv2[4];
#pragma unroll
    for (int g = 0; g < 4; g++) {
        bv1[g] = bc1[(w + 4 * g) * 16 + l15];
        bv2[g] = bc2[(w + 4 * g) * 16 + l15];
    }
    for (int t = 0; t < WINDOW; t++) {
        int cur = t & 1, prv = cur ^ 1;
        const size_t toff = (size_t)t * N_NODES * 64;
        // ======== LSTM 1 ========
        float4_ acc[2][4];
#pragma unroll
        for (int m = 0; m < 2; m++)
#pragma unroll
            for (int g = 0; g < 4; g++) acc[m][g] = (float4_){bv1[g], bv1[g], bv1[g], bv1[g]};
#pragma unroll
        for (int c = 0; c < 4; c++) {
            const bf* sp = (c < 2) ? h1b + toff : h2b + toff;
            int koff = (c & 1) * 32 + q * 8;
#pragma unroll
            for (int m = 0; m < 2; m++) {
                short8 a = *(const short8*)(sp + (size_t)(gnode0 + m * 16 + l15) * 64 + koff);
#pragma unroll
                for (int g = 0; g < 4; g++)
                    acc[m][g] = __builtin_amdgcn_mfma_f32_16x16x32_bf16(a, B1r[c][g], acc[m][g], 0, 0, 0);
            }
        }
        if (t > 0) {
#pragma unroll
            for (int c = 4; c < 6; c++) {
                int koff = (c & 1) * 32 + q * 8;
#pragma unroll
                for (int m = 0; m < 2; m++) {
                    short8 a = *(const short8*)&h1s[prv][m * 16 + l15][koff];
#pragma unroll
                    for (int g = 0; g < 4; g++)
                        acc[m][g] = __builtin_amdgcn_mfma_f32_16x16x32_bf16(a, B1r[c][g], acc[m][g], 0, 0, 0);
                }
            }
        }
#pragma unroll
        for (int m = 0; m < 2; m++)
#pragma unroll
            for (int reg = 0; reg < 4; reg++) {
                float gi = acc[m][0][reg], gf = acc[m][1][reg];
                float gg = acc[m][2][reg], go = acc[m][3][reg];
                float co = (t == 0) ? 0.f : c1[m][reg];
                float cn = sigf(gf) * co + sigf(gi) * tanhfast(gg);
                float hn = sigf(go) * tanhfast(cn);
                c1[m][reg] = cn;
                int nl = m * 16 + q * 4 + reg;
                h1s[cur][nl][w * 16 + l15] = f2b(hn);
                if (t == WINDOW - 1)
                    H1out[(size_t)(gnode0 + nl) * 64 + w * 16 + l15] = f2b(hn);
            }
        __syncthreads();   // h1s[cur] visible for LSTM2
        // ======== LSTM 2 ========
#pragma unroll
        for (int m = 0; m < 2; m++)
#pragma unroll
            for (int g = 0; g < 4; g++) acc[m][g] = (float4_){bv2[g], bv2[g], bv2[g], bv2[g]};
#pragma unroll
        for (int c = 0; c < 2; c++) {
            int koff = (c & 1) * 32 + q * 8;
#pragma unroll
            for (int m = 0; m < 2; m++) {
                short8 a = *(const short8*)&h1s[cur][m * 16 + l15][koff];
#pragma unroll
                for (int g = 0; g < 4; g++)
                    acc[m][g] = __builtin_amdgcn_mfma_f32_16x16x32_bf16(a, B2r[c][g], acc[m][g], 0, 0, 0);
            }
        }
        if (t > 0) {
#pragma unroll
            for (int c = 2; c < 4; c++) {
                int koff = (c & 1) * 32 + q * 8;
#pragma unroll
                for (int m = 0; m < 2; m++) {
                    short8 a = *(const short8*)&h2s[prv][m * 16 + l15][koff];
#pragma unroll
                    for (int g = 0; g < 4; g++)
                        acc[m][g] = __builtin_amdgcn_mfma_f32_16x16x32_bf16(a, B2r[c][g], acc[m][g], 0, 0, 0);
                }
            }
        }
#pragma unroll
        for (int m = 0; m < 2; m++)
#pragma unroll
            for (int reg = 0; reg < 4; reg++) {
                float gi = acc[m][0][reg], gf = acc[m][1][reg];
                float gg = acc[m][2][reg], go = acc[m][3][reg];
                float co = (t == 0) ? 0.f : c2[m][reg];
                float cn = sigf(gf) * co + sigf(gi) * tanhfast(gg);
                float hn = sigf(go) * tanhfast(cn);
                c2[m][reg] = cn;
                int nl = m * 16 + q * 4 + reg;
                h2s[cur][nl][w * 16 + l15] = f2b(hn);
                if (t == WINDOW - 1)
                    H2out[(size_t)(gnode0 + nl) * 64 + w * 16 + l15] = f2b(hn);
            }
        __syncthreads();   // h2s[cur] visible for next step
    }
}

// ------------- PQ = nodeemb @ Bpq, nodeemb built in LDS (fused) -------------
__global__ __launch_bounds__(256) void k_pq(const bf* H1, const bf* H2, const float* x,
                                            const bf* Bpqf, const float* dba, bf* PQb) {
    __shared__ bf ne[64][NER];
    int tid = threadIdx.x, w = tid >> 6, lane = tid & 63;
    int q = lane >> 4, l15 = lane & 15;
    int r0 = blockIdx.x * 64;
    for (int i = tid; i < 64 * 16; i += 256) {
        int rr = i >> 4, cc = (i & 15) * 4;
        int gr = r0 + rr;
        uint2 v1 = make_uint2(0u, 0u), v2 = make_uint2(0u, 0u);
        if (gr < N_NODES) {
            v1 = *(const uint2*)(H1 + (size_t)gr * 64 + cc);
            v2 = *(const uint2*)(H2 + (size_t)gr * 64 + cc);
        }
        *(uint2*)&ne[rr][cc] = v1;
        *(uint2*)&ne[rr][64 + cc] = v2;
    }
    for (int i = tid; i < 64 * 32; i += 256) {
        int rr = i >> 5, cc = 128 + (i & 31);
        int gr = r0 + rr;
        float v = 0.f;
        if (gr < N_NODES && cc < DHV) {
            int s = cc - 128;
            v = (s < 8) ? x[gr * IN_C + s] : x[(size_t)((s - 7) * N_NODES + gr) * IN_C + 7];
        }
        ne[rr][cc] = f2b(v);
    }
    __syncthreads();
    float4_ acc[18];
#pragma unroll
    for (int ct = 0; ct < 18; ct++) acc[ct] = (float4_){0.f, 0.f, 0.f, 0.f};
#pragma unroll
    for (int c = 0; c < 5; c++) {
        short8 a = *(const short8*)&ne[w * 16 + l15][c * 32 + q * 8];
#pragma unroll
        for (int ct = 0; ct < 18; ct++) {
            short8 b = *(const short8*)(Bpqf + (size_t)((ct * 5 + c) * 64 + lane) * 8);
            acc[ct] = __builtin_amdgcn_mfma_f32_16x16x32_bf16(a, b, acc[ct], 0, 0, 0);
        }
    }
#pragma unroll
    for (int reg = 0; reg < 4; reg++) {
        int nrow = r0 + w * 16 + q * 4 + reg;
        if (nrow < N_NODES)
#pragma unroll
            for (int ct = 0; ct < 18; ct++) {
                int col = ct * 16 + l15;
                float add = (ct < 9 && col < DHV) ? dba[col] : 0.f;
                PQb[(size_t)nrow * 288 + col] = f2b(acc[ct][reg] + add);
            }
    }
}

// decoder: 2 edges/wave, 32 lanes/edge, 8B loads; P' already has +dba
__global__ __launch_bounds__(256) void k_edge(const int* ewi, const bf* PQb,
                                              const float* dWb, const float* dbb, float* out) {
    int wv = (blockIdx.x * blockDim.x + threadIdx.x) >> 6;
    int half = (threadIdx.x >> 5) & 1, l = threadIdx.x & 31;
    int e = wv * 2 + half;
    if (e >= E_DEC) return;
    int src = ewi[e], trg = ewi[E_DEC + e];
    const bf* Pr = PQb + (size_t)src * 288;
    const bf* Qr = PQb + (size_t)trg * 288 + 144;
    float acc;
    {
        uint2 pv = *(const uint2*)(Pr + 4 * l);
        uint2 qv = *(const uint2*)(Qr + 4 * l);
        float4 wv4 = *(const float4*)(dWb + 4 * l);
        float s0 = fmaxf(bflo(pv.x) + bflo(qv.x), 0.f);
        float s1 = fmaxf(bfhi(pv.x) + bfhi(qv.x), 0.f);
        float s2 = fmaxf(bflo(pv.y) + bflo(qv.y), 0.f);
        float s3 = fmaxf(bfhi(pv.y) + bfhi(qv.y), 0.f);
        acc = s0 * wv4.x + s1 * wv4.y + s2 * wv4.z + s3 * wv4.w;
    }
    if (l < 4) {
        int u0 = 128 + 4 * l;
        uint2 pv = *(const uint2*)(Pr + u0);
        uint2 qv = *(const uint2*)(Qr + u0);
        float w0 = dWb[u0], w1 = dWb[u0 + 1], w2 = dWb[u0 + 2];
        float w3 = (u0 + 3 < DHV) ? dWb[u0 + 3] : 0.f;
        acc += fmaxf(bflo(pv.x) + bflo(qv.x), 0.f) * w0;
        acc += fmaxf(bfhi(pv.x) + bfhi(qv.x), 0.f) * w1;
        acc += fmaxf(bflo(pv.y) + bflo(qv.y), 0.f) * w2;
        acc += fmaxf(bfhi(pv.y) + bfhi(qv.y), 0.f) * w3;
    }
#pragma unroll
    for (int off = 16; off > 0; off >>= 1) acc += __shfl_xor(acc, off);
    if (l == 0) out[e] = acc + dbb[0];
}

// ---------------------------------------------------------------------------
extern "C" void kernel_launch(void* const* d_in, const int* in_sizes, int n_in,
                              void* d_out, int out_size, void* d_ws, size_t ws_size,
                              hipStream_t stream) {
    (void)in_sizes; (void)n_in; (void)out_size; (void)ws_size;
    const float* x    = (const float*)d_in[0];
    const float* ea   = (const float*)d_in[1];
    const int*   ei   = (const int*)d_in[2];
    const int*   ewi  = (const int*)d_in[3];
    const float* W1   = (const float*)d_in[4];
    const float* b1   = (const float*)d_in[5];
    const float* g1   = (const float*)d_in[6];
    const float* be1  = (const float*)d_in[7];
    const float* W2   = (const float*)d_in[8];
    const float* b2   = (const float*)d_in[9];
    const float* g2   = (const float*)d_in[10];
    const float* be2  = (const float*)d_in[11];
    const float* Wih1 = (const float*)d_in[12];
    const float* Whh1 = (const float*)d_in[13];
    const float* bih1 = (const float*)d_in[14];
    const float* bhh1 = (const float*)d_in[15];
    const float* Wih2 = (const float*)d_in[16];
    const float* Whh2 = (const float*)d_in[17];
    const float* bih2 = (const float*)d_in[18];
    const float* bhh2 = (const float*)d_in[19];
    const float* dWa  = (const float*)d_in[20];
    const float* dba  = (const float*)d_in[21];
    const float* dWb  = (const float*)d_in[22];
    const float* dbb  = (const float*)d_in[23];
    float* out = (float*)d_out;

    const size_t NSB = (size_t)N_BIG * 64;
    const size_t NS  = (size_t)N_NODES * 64;
    char* base = (char*)d_ws;
    size_t o = 0;
    float* dis  = (float*)(base + o); o += (size_t)N_BIG * 4;
    bf* PQb     = (bf*)(base + o);    o += NSB * 2;
    bf* hbufb   = (bf*)(base + o);    o += NSB * 2;
    bf* h1b     = (bf*)(base + o);    o += NSB * 2;
    bf* h2b     = (bf*)(base + o);    o += NSB * 2;
    bf* hs1     = (bf*)(base + o);    o += NS * 2;
    bf* hs2     = (bf*)(base + o);    o += NS * 2;
    bf* B1f     = (bf*)(base + o);    o += (size_t)16 * 6 * 64 * 8 * 2;
    bf* B2f     = (bf*)(base + o);    o += (size_t)16 * 4 * 64 * 8 * 2;
    bf* W2t     = (bf*)(base + o);    o += 64 * 64 * 2;
    bf* Bpqf    = (bf*)(base + o);    o += (size_t)18 * 5 * 64 * 8 * 2;
    float* bc1  = (float*)(base + o); o += 256 * 4;
    float* bc2  = (float*)(base + o); o += 256 * 4;
    float* stats= (float*)(base + o); o += 256 * 4;
    float* w2b  = (float*)(base + o); o += 64 * 4;
    float* AC   = (float*)(base + o); o += 128 * 4;
    float* bc1f = (float*)(base + o); o += 256 * 4;
    int* cnt    = (int*)(base + o);   o += (size_t)N_BIG * 4;
    int* ovfn   = (int*)(base + o);   o += 256 * 4;                // [0]=ovfn, [8..15]=cursor (zeroed with cnt)
    float4* ovf = (float4*)(base + o); o += (size_t)OVF_CAP * 16;
    unsigned int* bucket = (unsigned int*)(base + o); o += (size_t)N_BIG * CAP * 4;  // 20.5 MB
    float* part = (float*)(base + o); o += (size_t)20000 * 128 * 4;
    int* cursor = ovfn + 8;

    // ---- zero cnt+ovfn+cursor, then XCD-aware stealing fill + weight prep ----
    hipMemsetAsync(cnt, 0, ((size_t)N_BIG + 256) * 4, stream);
    k_prepfill<<<NFILL + 512, 256, 0, stream>>>(ei, ea, cnt, bucket, ovfn, cursor, ovf,
                                               Wih2, Whh2, bih1, bhh1, bih2, bhh2, dWa,
                                               B2f, bc1, bc2, Bpqf);
    // ---- dis + x@W1 fused ----
    k_xw1dis<<<N_BIG / 8, 256, 0, stream>>>(x, W1, cnt, bucket, ovfn, ovf, dis, hbufb);

    // ---- GCN layer 1 ----
    k_gcn_gather<<<N_BIG / 8, 256, 0, stream>>>(hbufb, dis, cnt, bucket, ovfn, ovf, b1, h1b, part);
    k_bnred<<<128, 256, 0, stream>>>(part, 20000, stats);
    k_fold1<<<1, 256, 0, stream>>>(W2, g1, be1, stats, W2t, w2b, AC);

    // ---- GCN layer 2 ----
    k_h1w2<<<2500, 256, 0, stream>>>(h1b, W2t, w2b, dis, hbufb);
    k_gcn_gather<<<N_BIG / 8, 256, 0, stream>>>(hbufb, dis, cnt, bucket, ovfn, ovf, b2, h2b, part);
    k_bnred<<<128, 256, 0, stream>>>(part, 20000, stats + 128);
    k_fold2<<<64, 256, 0, stream>>>(Wih1, Whh1, g2, be2, stats, AC, bih1, bhh1, B1f, bc1f);

    // ---- both LSTMs, all 8 steps, one launch ----
    k_lstm_fused<<<625, 256, 0, stream>>>(h1b, h2b, B1f, B2f, bc1f, bc2, hs1, hs2);

    // ---- decoder ----
    k_pq<<<313, 256, 0, stream>>>(hs1, hs2, x, Bpqf, dba, PQb);
    k_edge<<<E_DEC / 8, 256, 0, stream>>>(ewi, PQb, dWb, dbb, out);
}

// Round 19
// 575.741 us; speedup vs baseline: 2.5549x; 2.5549x over previous
//
#include <hip/hip_runtime.h>
#include <hip/hip_bf16.h>

#define IN_C 8
#define HID 64
#define N_NODES 20000
#define WINDOW 8
#define N_BIG 160000
#define NE 1600000
#define E_DEC 500000
#define DHV 143
#define EPSV 1e-5f
#define CAP 32
#define OVF_CAP 4096
#define NER 168   // padded LDS row stride (shorts) for the pq embedding tile
#define QS 16384.0f
#define IQS (1.0f / 16384.0f)
#define NPART 8
#define PART_SZ (N_BIG / NPART)     // 20000
#define NEB (NE / 256)              // 6250 edge chunks

typedef __hip_bfloat16 bf;
typedef __attribute__((ext_vector_type(8))) short short8;
typedef __attribute__((ext_vector_type(4))) float float4_;

__device__ __forceinline__ float b2f(bf v) { return __bfloat162float(v); }
__device__ __forceinline__ bf f2b(float v) { return __float2bfloat16(v); }
__device__ __forceinline__ float bflo(unsigned int u) { return __uint_as_float(u << 16); }
__device__ __forceinline__ float bfhi(unsigned int u) { return __uint_as_float(u & 0xffff0000u); }
__device__ __forceinline__ unsigned int packbf2(float lo, float hi) {
    unsigned int ul = __bfloat16_as_ushort(f2b(lo));
    unsigned int uh = __bfloat16_as_ushort(f2b(hi));
    return ul | (uh << 16);
}
__device__ __forceinline__ float sigf(float x) {
    return __builtin_amdgcn_rcpf(1.f + __expf(-x));
}
__device__ __forceinline__ float tanhfast(float x) {
    x = fminf(fmaxf(x, -15.f), 15.f);
    float e = __expf(2.f * x);
    return (e - 1.f) * __builtin_amdgcn_rcpf(e + 1.f);
}

// ------- XCD-partitioned bucket fill (1 atomic/edge) + prep grid-split -----
// blocks [0, 8*6250): edge fill, partition p = blockIdx&7 handles dest range
// [p*20000,(p+1)*20000). blocks [50000, 50512): weight conversion (prep).
// (round-17 configuration — measured best at 582us total)
__global__ __launch_bounds__(256) void k_prepfill(
    const int* ei, const float* ea, int* cnt, unsigned int* bucket, int* ovfn, float4* ovf,
    const float* Wih2, const float* Whh2, const float* bih1, const float* bhh1,
    const float* bih2, const float* bhh2, const float* dWa,
    bf* B2f, float* bc1, float* bc2, bf* Bpqf)
{
    int tid = threadIdx.x;
    if (blockIdx.x < NPART * NEB) {
        int p = blockIdx.x & (NPART - 1);
        int chunk = blockIdx.x >> 3;
        int e = chunk * 256 + tid;
        int c = ei[NE + e];
        if (c >= p * PART_SZ && c < (p + 1) * PART_SZ) {
            int r = ei[e];
            float a = ea[e];
            unsigned int q = (unsigned int)(a * QS + 0.5f);
            if (q > 16383u) q = 16383u;
            int pp = atomicAdd(&cnt[c], 1);
            if (pp < CAP) bucket[(size_t)c * CAP + pp] = ((unsigned int)r << 14) | q;
            else {
                int qq = atomicAdd(ovfn, 1);
                if (qq < OVF_CAP) ovf[qq] = make_float4(__int_as_float(c), __int_as_float(r), a, 0.f);
            }
        }
        return;
    }
    int i0 = (blockIdx.x - NPART * NEB) * 256 + tid;
    int stride = 512 * 256;
    for (int i = i0; i < 16 * 4 * 64 * 8; i += stride) {   // B2 fragments (K=128)
        int j = i & 7, lane = (i >> 3) & 63, r = i >> 9;
        int c = r & 3, ct = r >> 2;
        int q = lane >> 4, l15 = lane & 15;
        int n = ct * 16 + l15, k = c * 32 + q * 8 + j;
        B2f[i] = f2b((k < 64) ? Wih2[n * 64 + k] : Whh2[n * 64 + (k - 64)]);
    }
    for (int i = i0; i < 256; i += stride) {
        bc1[i] = bih1[i] + bhh1[i];
        bc2[i] = bih2[i] + bhh2[i];
    }
    for (int i = i0; i < 18 * 5 * 64 * 8; i += stride) {   // decoder fragments
        int j = i & 7, lane = (i >> 3) & 63, r = i >> 9;
        int c = r % 5, ct = r / 5;
        int q = lane >> 4, l15 = lane & 15;
        int n = ct * 16 + l15, k = c * 32 + q * 8 + j;
        float v = 0.f;
        if (k < DHV) {
            if (n < DHV) v = dWa[k * DHV + n];
            else if (n >= 144 && n < 144 + DHV) v = dWa[(DHV + k) * DHV + (n - 144)];
        }
        Bpqf[i] = f2b(v);
    }
}

// -------- fused: deg from buckets -> dis; write dis*(x@W1) once ------------
__global__ __launch_bounds__(256) void k_xw1dis(const float* x, const float* W1,
        const int* cnt, const unsigned int* bucket, const int* ovfn, const float4* ovf,
        float* dis, bf* hbufb) {
    __shared__ float Ws[8][64];
    __shared__ float xs[8][8];
    int tid = threadIdx.x;
    Ws[tid >> 6][tid & 63] = W1[tid];
    Ws[4 + (tid >> 6)][tid & 63] = W1[256 + tid];
    int nb0 = blockIdx.x * 8;
    if (tid < 64) xs[tid >> 3][tid & 7] = x[nb0 * IN_C + tid];
    __syncthreads();
    int wv = tid >> 6, half = (tid >> 5) & 1, l = tid & 31;
    int nl = wv * 2 + half;
    int c = nb0 + nl;
    int n = cnt[c];
    int nbk = (n < CAP) ? n : CAP;
    float s = 0.f;
    for (int i = l; i < nbk; i += 32) s += (float)(bucket[(size_t)c * CAP + i] & 0x3FFFu);
    s *= IQS;
    if (n > CAP) {
        int m = *ovfn; if (m > OVF_CAP) m = OVF_CAP;
        for (int i = l; i < m; i += 32) {
            float4 v = ovf[i];
            if (__float_as_int(v.x) == c) s += v.z;
        }
    }
#pragma unroll
    for (int off = 16; off > 0; off >>= 1) s += __shfl_xor(s, off);
    float dv = rsqrtf(fmaxf(1.f + s, EPSV));
    if (l == 0) dis[c] = dv;
    float a0 = 0.f, a1 = 0.f;
#pragma unroll
    for (int k = 0; k < IN_C; k++) {
        float xv = xs[nl][k];
        a0 += xv * Ws[k][2 * l];
        a1 += xv * Ws[k][2 * l + 1];
    }
    *(unsigned int*)(hbufb + (size_t)c * 64 + 2 * l) = packbf2(dv * a0, dv * a1);
}

// ---------------- GCN aggregation (bucket gather) + fused BN partial stats --
__global__ __launch_bounds__(256) void k_gcn_gather(const bf* h, const float* dis, const int* cnt,
                             const unsigned int* bucket, const int* ovfn, const float4* ovf,
                             const float* bias, bf* outb, float* part) {
    __shared__ float4 red[256];
    int tid = threadIdx.x;
    int wv = (blockIdx.x * 256 + tid) >> 6;
    int half = (tid >> 5) & 1, l = tid & 31;
    int c = wv * 2 + half;                 // grid exact: c < N_BIG always
    unsigned int hv = *(const unsigned int*)(h + (size_t)c * 64 + 2 * l);
    float ax = bflo(hv), ay = bfhi(hv);
    size_t o = (size_t)c * CAP;
    int nfull = cnt[c];
    int n = (nfull < CAP) ? nfull : CAP;
    int e = 0;
    for (; e + 8 <= n; e += 8) {
        unsigned int p[8];
#pragma unroll
        for (int j = 0; j < 8; j++) p[j] = bucket[o + e + j];
        unsigned int v[8];
#pragma unroll
        for (int j = 0; j < 8; j++)
            v[j] = *(const unsigned int*)(h + (size_t)(p[j] >> 14) * 64 + 2 * l);
#pragma unroll
        for (int j = 0; j < 8; j++) {
            float a = (float)(p[j] & 0x3FFFu) * IQS;
            ax += a * bflo(v[j]); ay += a * bfhi(v[j]);
        }
    }
    for (; e + 4 <= n; e += 4) {
        unsigned int p[4];
#pragma unroll
        for (int j = 0; j < 4; j++) p[j] = bucket[o + e + j];
        unsigned int v[4];
#pragma unroll
        for (int j = 0; j < 4; j++)
            v[j] = *(const unsigned int*)(h + (size_t)(p[j] >> 14) * 64 + 2 * l);
#pragma unroll
        for (int j = 0; j < 4; j++) {
            float a = (float)(p[j] & 0x3FFFu) * IQS;
            ax += a * bflo(v[j]); ay += a * bfhi(v[j]);
        }
    }
    for (; e < n; e++) {
        unsigned int p = bucket[o + e];
        unsigned int v = *(const unsigned int*)(h + (size_t)(p >> 14) * 64 + 2 * l);
        float a = (float)(p & 0x3FFFu) * IQS;
        ax += a * bflo(v);
        ay += a * bfhi(v);
    }
    if (nfull > CAP) {      // practically never
        int m = *ovfn; if (m > OVF_CAP) m = OVF_CAP;
        for (int i = 0; i < m; i++) {
            float4 v = ovf[i];
            if (__float_as_int(v.x) == c) {
                unsigned int hw = *(const unsigned int*)(h + (size_t)__float_as_int(v.y) * 64 + 2 * l);
                ax += v.z * bflo(hw);
                ay += v.z * bfhi(hw);
            }
        }
    }
    float dv = dis[c];
    float2 bv = *(const float2*)(bias + 2 * l);
    float vx = fmaxf(dv * ax + bv.x, 0.f);
    float vy = fmaxf(dv * ay + bv.y, 0.f);
    *(unsigned int*)(outb + (size_t)c * 64 + 2 * l) = packbf2(vx, vy);
    // ---- BN partial stats (fp32, pre-round) ----
    red[tid] = make_float4(vx, vy, vx * vx, vy * vy);
    __syncthreads();
    if (tid < 32) {
        float4 s = make_float4(0.f, 0.f, 0.f, 0.f);
#pragma unroll
        for (int i = 0; i < 8; i++) {
            float4 v = red[((i >> 1) << 6) + ((i & 1) << 5) + tid];
            s.x += v.x; s.y += v.y; s.z += v.z; s.w += v.w;
        }
        float* pb = part + (size_t)blockIdx.x * 128;
        pb[2 * tid] = s.x; pb[2 * tid + 1] = s.y;
        pb[64 + 2 * tid] = s.z; pb[64 + 2 * tid + 1] = s.w;
    }
}

// ---------------- reduce per-block BN partials ------------------------------
__global__ __launch_bounds__(256) void k_bnred(const float* part, int nblk, float* stats_out) {
    __shared__ float s[256];
    float acc = 0.f;
    for (int b = threadIdx.x; b < nblk; b += 256) acc += part[(size_t)b * 128 + blockIdx.x];
    s[threadIdx.x] = acc;
    __syncthreads();
    for (int off = 128; off; off >>= 1) {
        if (threadIdx.x < off) s[threadIdx.x] += s[threadIdx.x + off];
        __syncthreads();
    }
    if (threadIdx.x == 0) stats_out[blockIdx.x] = s[0];
}

// ------------------------------- fold BN1 affine into W2^T + bias ----------
__global__ __launch_bounds__(256) void k_fold1(const float* W2, const float* g1, const float* be1,
                                               const float* stats, bf* W2t, float* w2b, float* AC) {
    __shared__ float A[64], C[64];
    int tid = threadIdx.x;
    if (tid < 64) {
        float m = stats[tid] * (1.f / (float)N_BIG);
        float var = stats[64 + tid] * (1.f / (float)N_BIG) - m * m;
        float a = g1[tid] * rsqrtf(var + EPSV);
        float c = be1[tid] - m * a;
        A[tid] = a; C[tid] = c;
        AC[tid] = a; AC[64 + tid] = c;
    }
    __syncthreads();
    for (int i = tid; i < 4096; i += 256) {
        int n = i >> 6, k = i & 63;
        W2t[i] = f2b(W2[k * 64 + n] * A[k]);
    }
    if (tid < 64) {
        float s = 0.f;
        for (int k = 0; k < 64; k++) s += C[k] * W2[k * 64 + tid];
        w2b[tid] = s;
    }
}

// -------- fold BN1/BN2 affine into LSTM1 weights (B1f fragments) + bias ----
__global__ void k_fold2(const float* Wih1, const float* Whh1,
                        const float* g2, const float* be2, const float* stats,
                        const float* AC, const float* bih1, const float* bhh1,
                        bf* B1f, float* bc1f) {
    int i0 = blockIdx.x * blockDim.x + threadIdx.x;
    int stride = gridDim.x * blockDim.x;
    for (int i = i0; i < 16 * 6 * 64 * 8; i += stride) {
        int j = i & 7, lane = (i >> 3) & 63, r = i >> 9;
        int c = r % 6, ct = r / 6;
        int q = lane >> 4, l15 = lane & 15;
        int n = ct * 16 + l15, k = c * 32 + q * 8 + j;
        float w = (k < 128) ? Wih1[n * 128 + k] : Whh1[n * 64 + (k - 128)];
        float scale = 1.f;
        if (k < 64) scale = AC[k];
        else if (k < 128) {
            int ch = k - 64;
            float m = stats[128 + ch] * (1.f / (float)N_BIG);
            float var = stats[192 + ch] * (1.f / (float)N_BIG) - m * m;
            scale = g2[ch] * rsqrtf(var + EPSV);
        }
        B1f[i] = f2b(w * scale);
    }
    for (int n = i0; n < 256; n += stride) {
        float s = bih1[n] + bhh1[n];
        for (int k = 0; k < 64; k++) s += AC[64 + k] * Wih1[n * 128 + k];
        for (int ch = 0; ch < 64; ch++) {
            float m = stats[128 + ch] * (1.f / (float)N_BIG);
            float var = stats[192 + ch] * (1.f / (float)N_BIG) - m * m;
            float a = g2[ch] * rsqrtf(var + EPSV);
            float c2v = be2[ch] - m * a;
            s += c2v * Wih1[n * 128 + 64 + ch];
        }
        bc1f[n] = s;
    }
}

// ------------- h1_raw @ (A1-scaled W2) + w2b, epilogue x dis (bf16 MFMA) ----
__global__ __launch_bounds__(256) void k_h1w2(const bf* h1b, const bf* W2t, const float* w2b,
                                              const float* dis, bf* outb) {
    int tid = threadIdx.x, w = tid >> 6, lane = tid & 63;
    int q = lane >> 4, l15 = lane & 15;
    size_t r0 = (size_t)blockIdx.x * 64 + w * 16;
    float4_ acc[4];
#pragma unroll
    for (int ct = 0; ct < 4; ct++) acc[ct] = (float4_){0.f, 0.f, 0.f, 0.f};
#pragma unroll
    for (int c = 0; c < 2; c++) {
        int koff = c * 32 + q * 8;
        short8 a = *(const short8*)(h1b + (r0 + l15) * 64 + koff);
#pragma unroll
        for (int ct = 0; ct < 4; ct++) {
            short8 b = *(const short8*)(W2t + (size_t)(ct * 16 + l15) * 64 + koff);
            acc[ct] = __builtin_amdgcn_mfma_f32_16x16x32_bf16(a, b, acc[ct], 0, 0, 0);
        }
    }
    size_t node0 = r0 + q * 4;
#pragma unroll
    for (int reg = 0; reg < 4; reg++) {
        float dv = dis[node0 + reg];
#pragma unroll
        for (int ct = 0; ct < 4; ct++)
            outb[(node0 + reg) * 64 + ct * 16 + l15] = f2b(dv * (acc[ct][reg] + w2b[ct * 16 + l15]));
    }
}

// ----------------------------------------- fully fused double LSTM (MFMA) ---
__global__ __launch_bounds__(256, 1) void k_lstm_fused(
    const bf* h1b, const bf* h2b, const bf* B1f, const bf* B2f,
    const float* bc1, const float* bc2, bf* H1out, bf* H2out)
{
    __shared__ bf h1s[2][32][72];
    __shared__ bf h2s[2][32][72];
    int tid = threadIdx.x, w = tid >> 6, lane = tid & 63;
    int q = lane >> 4, l15 = lane & 15;
    int gnode0 = blockIdx.x * 32;
    short8 B1r[6][4];
    short8 B2r[4][4];
#pragma unroll
    for (int c = 0; c < 6; c++)
#pragma unroll
        for (int g = 0; g < 4; g++)
            B1r[c][g] = *(const short8*)(B1f + (size_t)(((w + 4 * g) * 6 + c) * 64 + lane) * 8);
#pragma unroll
    for (int c = 0; c < 4; c++)
#pragma unroll
        for (int g = 0; g < 4; g++)
            B2r[c][g] = *(const short8*)(B2f + (size_t)(((w + 4 * g) * 4 + c) * 64 + lane) * 8);
    float c1[2][4] = {}, c2[2][4] = {};
    float bv1[4], bv2[4];
#pragma unroll
    for (int g = 0; g < 4; g++) {
        bv1[g] = bc1[(w + 4 * g) * 16 + l15];
        bv2[g] = bc2[(w + 4 * g) * 16 + l15];
    }
    for (int t = 0; t < WINDOW; t++) {
        int cur = t & 1, prv = cur ^ 1;
        const size_t toff = (size_t)t * N_NODES * 64;
        // ======== LSTM 1 ========
        float4_ acc[2][4];
#pragma unroll
        for (int m = 0; m < 2; m++)
#pragma unroll
            for (int g = 0; g < 4; g++) acc[m][g] = (float4_){bv1[g], bv1[g], bv1[g], bv1[g]};
#pragma unroll
        for (int c = 0; c < 4; c++) {
            const bf* sp = (c < 2) ? h1b + toff : h2b + toff;
            int koff = (c & 1) * 32 + q * 8;
#pragma unroll
            for (int m = 0; m < 2; m++) {
                short8 a = *(const short8*)(sp + (size_t)(gnode0 + m * 16 + l15) * 64 + koff);
#pragma unroll
                for (int g = 0; g < 4; g++)
                    acc[m][g] = __builtin_amdgcn_mfma_f32_16x16x32_bf16(a, B1r[c][g], acc[m][g], 0, 0, 0);
            }
        }
        if (t > 0) {
#pragma unroll
            for (int c = 4; c < 6; c++) {
                int koff = (c & 1) * 32 + q * 8;
#pragma unroll
                for (int m = 0; m < 2; m++) {
                    short8 a = *(const short8*)&h1s[prv][m * 16 + l15][koff];
#pragma unroll
                    for (int g = 0; g < 4; g++)
                        acc[m][g] = __builtin_amdgcn_mfma_f32_16x16x32_bf16(a, B1r[c][g], acc[m][g], 0, 0, 0);
                }
            }
        }
#pragma unroll
        for (int m = 0; m < 2; m++)
#pragma unroll
            for (int reg = 0; reg < 4; reg++) {
                float gi = acc[m][0][reg], gf = acc[m][1][reg];
                float gg = acc[m][2][reg], go = acc[m][3][reg];
                float co = (t == 0) ? 0.f : c1[m][reg];
                float cn = sigf(gf) * co + sigf(gi) * tanhfast(gg);
                float hn = sigf(go) * tanhfast(cn);
                c1[m][reg] = cn;
                int nl = m * 16 + q * 4 + reg;
                h1s[cur][nl][w * 16 + l15] = f2b(hn);
                if (t == WINDOW - 1)
                    H1out[(size_t)(gnode0 + nl) * 64 + w * 16 + l15] = f2b(hn);
            }
        __syncthreads();   // h1s[cur] visible for LSTM2
        // ======== LSTM 2 ========
#pragma unroll
        for (int m = 0; m < 2; m++)
#pragma unroll
            for (int g = 0; g < 4; g++) acc[m][g] = (float4_){bv2[g], bv2[g], bv2[g], bv2[g]};
#pragma unroll
        for (int c = 0; c < 2; c++) {
            int koff = (c & 1) * 32 + q * 8;
#pragma unroll
            for (int m = 0; m < 2; m++) {
                short8 a = *(const short8*)&h1s[cur][m * 16 + l15][koff];
#pragma unroll
                for (int g = 0; g < 4; g++)
                    acc[m][g] = __builtin_amdgcn_mfma_f32_16x16x32_bf16(a, B2r[c][g], acc[m][g], 0, 0, 0);
            }
        }
        if (t > 0) {
#pragma unroll
            for (int c = 2; c < 4; c++) {
                int koff = (c & 1) * 32 + q * 8;
#pragma unroll
                for (int m = 0; m < 2; m++) {
                    short8 a = *(const short8*)&h2s[prv][m * 16 + l15][koff];
#pragma unroll
                    for (int g = 0; g < 4; g++)
                        acc[m][g] = __builtin_amdgcn_mfma_f32_16x16x32_bf16(a, B2r[c][g], acc[m][g], 0, 0, 0);
                }
            }
        }
#pragma unroll
        for (int m = 0; m < 2; m++)
#pragma unroll
            for (int reg = 0; reg < 4; reg++) {
                float gi = acc[m][0][reg], gf = acc[m][1][reg];
                float gg = acc[m][2][reg], go = acc[m][3][reg];
                float co = (t == 0) ? 0.f : c2[m][reg];
                float cn = sigf(gf) * co + sigf(gi) * tanhfast(gg);
                float hn = sigf(go) * tanhfast(cn);
                c2[m][reg] = cn;
                int nl = m * 16 + q * 4 + reg;
                h2s[cur][nl][w * 16 + l15] = f2b(hn);
                if (t == WINDOW - 1)
                    H2out[(size_t)(gnode0 + nl) * 64 + w * 16 + l15] = f2b(hn);
            }
        __syncthreads();   // h2s[cur] visible for next step
    }
}

// ------------- PQ = nodeemb @ Bpq, nodeemb built in LDS (fused) -------------
__global__ __launch_bounds__(256) void k_pq(const bf* H1, const bf* H2, const float* x,
                                            const bf* Bpqf, const float* dba, bf* PQb) {
    __shared__ bf ne[64][NER];
    int tid = threadIdx.x, w = tid >> 6, lane = tid & 63;
    int q = lane >> 4, l15 = lane & 15;
    int r0 = blockIdx.x * 64;
    for (int i = tid; i < 64 * 16; i += 256) {
        int rr = i >> 4, cc = (i & 15) * 4;
        int gr = r0 + rr;
        uint2 v1 = make_uint2(0u, 0u), v2 = make_uint2(0u, 0u);
        if (gr < N_NODES) {
            v1 = *(const uint2*)(H1 + (size_t)gr * 64 + cc);
            v2 = *(const uint2*)(H2 + (size_t)gr * 64 + cc);
        }
        *(uint2*)&ne[rr][cc] = v1;
        *(uint2*)&ne[rr][64 + cc] = v2;
    }
    for (int i = tid; i < 64 * 32; i += 256) {
        int rr = i >> 5, cc = 128 + (i & 31);
        int gr = r0 + rr;
        float v = 0.f;
        if (gr < N_NODES && cc < DHV) {
            int s = cc - 128;
            v = (s < 8) ? x[gr * IN_C + s] : x[(size_t)((s - 7) * N_NODES + gr) * IN_C + 7];
        }
        ne[rr][cc] = f2b(v);
    }
    __syncthreads();
    float4_ acc[18];
#pragma unroll
    for (int ct = 0; ct < 18; ct++) acc[ct] = (float4_){0.f, 0.f, 0.f, 0.f};
#pragma unroll
    for (int c = 0; c < 5; c++) {
        short8 a = *(const short8*)&ne[w * 16 + l15][c * 32 + q * 8];
#pragma unroll
        for (int ct = 0; ct < 18; ct++) {
            short8 b = *(const short8*)(Bpqf + (size_t)((ct * 5 + c) * 64 + lane) * 8);
            acc[ct] = __builtin_amdgcn_mfma_f32_16x16x32_bf16(a, b, acc[ct], 0, 0, 0);
        }
    }
#pragma unroll
    for (int reg = 0; reg < 4; reg++) {
        int nrow = r0 + w * 16 + q * 4 + reg;
        if (nrow < N_NODES)
#pragma unroll
            for (int ct = 0; ct < 18; ct++) {
                int col = ct * 16 + l15;
                float add = (ct < 9 && col < DHV) ? dba[col] : 0.f;
                PQb[(size_t)nrow * 288 + col] = f2b(acc[ct][reg] + add);
            }
    }
}

// decoder: 2 edges/wave, 32 lanes/edge, 8B loads; P' already has +dba
__global__ __launch_bounds__(256) void k_edge(const int* ewi, const bf* PQb,
                                              const float* dWb, const float* dbb, float* out) {
    int wv = (blockIdx.x * blockDim.x + threadIdx.x) >> 6;
    int half = (threadIdx.x >> 5) & 1, l = threadIdx.x & 31;
    int e = wv * 2 + half;
    if (e >= E_DEC) return;
    int src = ewi[e], trg = ewi[E_DEC + e];
    const bf* Pr = PQb + (size_t)src * 288;
    const bf* Qr = PQb + (size_t)trg * 288 + 144;
    float acc;
    {
        uint2 pv = *(const uint2*)(Pr + 4 * l);
        uint2 qv = *(const uint2*)(Qr + 4 * l);
        float4 wv4 = *(const float4*)(dWb + 4 * l);
        float s0 = fmaxf(bflo(pv.x) + bflo(qv.x), 0.f);
        float s1 = fmaxf(bfhi(pv.x) + bfhi(qv.x), 0.f);
        float s2 = fmaxf(bflo(pv.y) + bflo(qv.y), 0.f);
        float s3 = fmaxf(bfhi(pv.y) + bfhi(qv.y), 0.f);
        acc = s0 * wv4.x + s1 * wv4.y + s2 * wv4.z + s3 * wv4.w;
    }
    if (l < 4) {
        int u0 = 128 + 4 * l;
        uint2 pv = *(const uint2*)(Pr + u0);
        uint2 qv = *(const uint2*)(Qr + u0);
        float w0 = dWb[u0], w1 = dWb[u0 + 1], w2 = dWb[u0 + 2];
        float w3 = (u0 + 3 < DHV) ? dWb[u0 + 3] : 0.f;
        acc += fmaxf(bflo(pv.x) + bflo(qv.x), 0.f) * w0;
        acc += fmaxf(bfhi(pv.x) + bfhi(qv.x), 0.f) * w1;
        acc += fmaxf(bflo(pv.y) + bflo(qv.y), 0.f) * w2;
        acc += fmaxf(bfhi(pv.y) + bfhi(qv.y), 0.f) * w3;
    }
#pragma unroll
    for (int off = 16; off > 0; off >>= 1) acc += __shfl_xor(acc, off);
    if (l == 0) out[e] = acc + dbb[0];
}

// ---------------------------------------------------------------------------
extern "C" void kernel_launch(void* const* d_in, const int* in_sizes, int n_in,
                              void* d_out, int out_size, void* d_ws, size_t ws_size,
                              hipStream_t stream) {
    (void)in_sizes; (void)n_in; (void)out_size; (void)ws_size;
    const float* x    = (const float*)d_in[0];
    const float* ea   = (const float*)d_in[1];
    const int*   ei   = (const int*)d_in[2];
    const int*   ewi  = (const int*)d_in[3];
    const float* W1   = (const float*)d_in[4];
    const float* b1   = (const float*)d_in[5];
    const float* g1   = (const float*)d_in[6];
    const float* be1  = (const float*)d_in[7];
    const float* W2   = (const float*)d_in[8];
    const float* b2   = (const float*)d_in[9];
    const float* g2   = (const float*)d_in[10];
    const float* be2  = (const float*)d_in[11];
    const float* Wih1 = (const float*)d_in[12];
    const float* Whh1 = (const float*)d_in[13];
    const float* bih1 = (const float*)d_in[14];
    const float* bhh1 = (const float*)d_in[15];
    const float* Wih2 = (const float*)d_in[16];
    const float* Whh2 = (const float*)d_in[17];
    const float* bih2 = (const float*)d_in[18];
    const float* bhh2 = (const float*)d_in[19];
    const float* dWa  = (const float*)d_in[20];
    const float* dba  = (const float*)d_in[21];
    const float* dWb  = (const float*)d_in[22];
    const float* dbb  = (const float*)d_in[23];
    float* out = (float*)d_out;

    const size_t NSB = (size_t)N_BIG * 64;
    const size_t NS  = (size_t)N_NODES * 64;
    char* base = (char*)d_ws;
    size_t o = 0;
    float* dis  = (float*)(base + o); o += (size_t)N_BIG * 4;
    bf* PQb     = (bf*)(base + o);    o += NSB * 2;
    bf* hbufb   = (bf*)(base + o);    o += NSB * 2;
    bf* h1b     = (bf*)(base + o);    o += NSB * 2;
    bf* h2b     = (bf*)(base + o);    o += NSB * 2;
    bf* hs1     = (bf*)(base + o);    o += NS * 2;
    bf* hs2     = (bf*)(base + o);    o += NS * 2;
    bf* B1f     = (bf*)(base + o);    o += (size_t)16 * 6 * 64 * 8 * 2;
    bf* B2f     = (bf*)(base + o);    o += (size_t)16 * 4 * 64 * 8 * 2;
    bf* W2t     = (bf*)(base + o);    o += 64 * 64 * 2;
    bf* Bpqf    = (bf*)(base + o);    o += (size_t)18 * 5 * 64 * 8 * 2;
    float* bc1  = (float*)(base + o); o += 256 * 4;
    float* bc2  = (float*)(base + o); o += 256 * 4;
    float* stats= (float*)(base + o); o += 256 * 4;
    float* w2b  = (float*)(base + o); o += 64 * 4;
    float* AC   = (float*)(base + o); o += 128 * 4;
    float* bc1f = (float*)(base + o); o += 256 * 4;
    int* cnt    = (int*)(base + o);   o += (size_t)N_BIG * 4;
    int* ovfn   = (int*)(base + o);   o += 256 * 4;                // zeroed with cnt
    float4* ovf = (float4*)(base + o); o += (size_t)OVF_CAP * 16;
    unsigned int* bucket = (unsigned int*)(base + o); o += (size_t)N_BIG * CAP * 4;  // 20.5 MB
    float* part = (float*)(base + o); o += (size_t)20000 * 128 * 4;

    // ---- zero cnt+ovfn, then XCD-partitioned bucket build + weight prep ----
    hipMemsetAsync(cnt, 0, ((size_t)N_BIG + 256) * 4, stream);
    k_prepfill<<<NPART * NEB + 512, 256, 0, stream>>>(ei, ea, cnt, bucket, ovfn, ovf,
                                               Wih2, Whh2, bih1, bhh1, bih2, bhh2, dWa,
                                               B2f, bc1, bc2, Bpqf);
    // ---- dis + x@W1 fused ----
    k_xw1dis<<<N_BIG / 8, 256, 0, stream>>>(x, W1, cnt, bucket, ovfn, ovf, dis, hbufb);

    // ---- GCN layer 1 ----
    k_gcn_gather<<<N_BIG / 8, 256, 0, stream>>>(hbufb, dis, cnt, bucket, ovfn, ovf, b1, h1b, part);
    k_bnred<<<128, 256, 0, stream>>>(part, 20000, stats);
    k_fold1<<<1, 256, 0, stream>>>(W2, g1, be1, stats, W2t, w2b, AC);

    // ---- GCN layer 2 ----
    k_h1w2<<<2500, 256, 0, stream>>>(h1b, W2t, w2b, dis, hbufb);
    k_gcn_gather<<<N_BIG / 8, 256, 0, stream>>>(hbufb, dis, cnt, bucket, ovfn, ovf, b2, h2b, part);
    k_bnred<<<128, 256, 0, stream>>>(part, 20000, stats + 128);
    k_fold2<<<64, 256, 0, stream>>>(Wih1, Whh1, g2, be2, stats, AC, bih1, bhh1, B1f, bc1f);

    // ---- both LSTMs, all 8 steps, one launch ----
    k_lstm_fused<<<625, 256, 0, stream>>>(h1b, h2b, B1f, B2f, bc1f, bc2, hs1, hs2);

    // ---- decoder ----
    k_pq<<<313, 256, 0, stream>>>(hs1, hs2, x, Bpqf, dba, PQb);
    k_edge<<<E_DEC / 8, 256, 0, stream>>>(ewi, PQb, dWb, dbb, out);
}